// Round 8
// baseline (847.827 us; speedup 1.0000x reference)
//
#include <hip/hip_runtime.h>
#include <math.h>

typedef unsigned int uint;
typedef unsigned short ushort;
typedef short s16x8 __attribute__((ext_vector_type(8)));
typedef float f32x4 __attribute__((ext_vector_type(4)));
typedef uint u32x4 __attribute__((ext_vector_type(4)));

#define L     880
#define LP    896
#define NC    64
#define WSZ   (NC * LP)
#define DS    48
#define OUTD  96
#define KCV   3072
#define NZ    3
#define NBLK  512

// ws layout (float offsets); 11 bf16 E planes then WF/WB/KDT/U/part/barrier
#define OFF_E    0
#define OFF_WF   4415488                    // 64 slabs f32
#define OFF_WB   (OFF_WF + 64 * WSZ)        // 64 slabs bf16
#define OFF_KDT  (OFF_WB + 64 * WSZ / 2)    // 896x3072 bf16
#define OFF_U    (OFF_KDT + LP * KCV / 2)   // 256x3072 bf16
#define OFF_PART (OFF_U + 256 * KCV / 2)    // NZ x 256 x 896 f32
#define OFF_BAR  (OFF_PART + NZ * 256 * LP) // 64 uints: cnt @0, gen @32
// total ~49.5 MiB

__device__ inline ushort f2b(float f) {
  uint u = __builtin_bit_cast(uint, f);
  u += 0x7fffu + ((u >> 16) & 1u);
  return (ushort)(u >> 16);
}
__device__ inline float b2f(ushort b) {
  uint u = ((uint)b) << 16;
  return __builtin_bit_cast(float, u);
}

// ---- grid barrier: monotone arrival counter + generation flag (separate cachelines).
// Arrival: one device-scope RMW per block. Wait: device-scope atomic LOADs (no RMW
// contention) with s_sleep backoff. Barrier `target` passes when cnt reaches target*NBLK.
__device__ __forceinline__ void gbar(uint* bar, uint target) {
  __syncthreads();
  if (threadIdx.x == 0) {
    uint* cnt = bar;
    uint* gen = bar + 32;
    uint prev = __hip_atomic_fetch_add(cnt, 1u, __ATOMIC_ACQ_REL, __HIP_MEMORY_SCOPE_AGENT);
    if (prev == target * NBLK - 1u) {
      __hip_atomic_store(gen, target, __ATOMIC_RELEASE, __HIP_MEMORY_SCOPE_AGENT);
    } else {
      while (__hip_atomic_load(gen, __ATOMIC_ACQUIRE, __HIP_MEMORY_SCOPE_AGENT) < target)
        __builtin_amdgcn_s_sleep(4);
    }
  }
  __syncthreads();
}

__global__ void k_init(uint* bar) {
  if (threadIdx.x < 64) bar[threadIdx.x] = 0;
}

// ---- 64x64xK GEMM core (round-4 geometry): C[m][n] = sum_k Ag[m][k]*Bg[n][k] ----
__device__ __forceinline__ void gemm64(const ushort* __restrict__ Ag,
                                       const ushort* __restrict__ Bg,
                                       int Kdim, int kIters, int kOff, int m0, int n0,
                                       int tid, ushort (*As)[72], ushort (*Bs)[72],
                                       f32x4 acc[2][2]) {
  const int r = tid >> 2, kq = (tid & 3) * 16;
  const ushort* aptr = Ag + (size_t)(m0 + r) * Kdim + kOff + kq;
  const ushort* bptr = Bg + (size_t)(n0 + r) * Kdim + kOff + kq;
  const int wv = tid >> 6, lane = tid & 63;
  const int wm = (wv >> 1) * 32, wn = (wv & 1) * 32;
  const int lr = lane & 15, lg = lane >> 4;
  acc[0][0] = f32x4{0.f, 0.f, 0.f, 0.f};
  acc[0][1] = f32x4{0.f, 0.f, 0.f, 0.f};
  acc[1][0] = f32x4{0.f, 0.f, 0.f, 0.f};
  acc[1][1] = f32x4{0.f, 0.f, 0.f, 0.f};
  u32x4 ra0 = *(const u32x4*)aptr;
  u32x4 ra1 = *(const u32x4*)(aptr + 8);
  u32x4 rb0 = *(const u32x4*)bptr;
  u32x4 rb1 = *(const u32x4*)(bptr + 8);
  __syncthreads();                       // protect LDS vs previous task's readers
  for (int it = 0; it < kIters; ++it) {
    const int cur = (it & 1) * 64;
    *(u32x4*)&As[cur + r][kq]     = ra0;
    *(u32x4*)&As[cur + r][kq + 8] = ra1;
    *(u32x4*)&Bs[cur + r][kq]     = rb0;
    *(u32x4*)&Bs[cur + r][kq + 8] = rb1;
    __syncthreads();
    if (it + 1 < kIters) {
      ra0 = *(const u32x4*)(aptr + (it + 1) * 64);
      ra1 = *(const u32x4*)(aptr + (it + 1) * 64 + 8);
      rb0 = *(const u32x4*)(bptr + (it + 1) * 64);
      rb1 = *(const u32x4*)(bptr + (it + 1) * 64 + 8);
    }
#pragma unroll
    for (int k2 = 0; k2 < 2; ++k2) {
      s16x8 a0 = *(const s16x8*)&As[cur + wm + lr][k2 * 32 + lg * 8];
      s16x8 a1 = *(const s16x8*)&As[cur + wm + 16 + lr][k2 * 32 + lg * 8];
      s16x8 b0 = *(const s16x8*)&Bs[cur + wn + lr][k2 * 32 + lg * 8];
      s16x8 b1 = *(const s16x8*)&Bs[cur + wn + 16 + lr][k2 * 32 + lg * 8];
      acc[0][0] = __builtin_amdgcn_mfma_f32_16x16x32_bf16(a0, b0, acc[0][0], 0, 0, 0);
      acc[0][1] = __builtin_amdgcn_mfma_f32_16x16x32_bf16(a0, b1, acc[0][1], 0, 0, 0);
      acc[1][0] = __builtin_amdgcn_mfma_f32_16x16x32_bf16(a1, b0, acc[1][0], 0, 0, 0);
      acc[1][1] = __builtin_amdgcn_mfma_f32_16x16x32_bf16(a1, b1, acc[1][1], 0, 0, 0);
    }
  }
}

// ---- kd task: KDT[l0..+63][j*48+d] = W_j[d][l] - W_{j-1}[d][l] (j=63 -> zero pad) ----
__device__ __forceinline__ void kd_body(const float* __restrict__ WF, ushort* __restrict__ KDT,
                                        int j, int l0, int tid, float (*D)[65]) {
  __syncthreads();
  if (j < 63) {
    const float* Wj = WF + (size_t)j * WSZ;
    for (int e = tid; e < 48 * 64; e += 256) {
      int d = e >> 6, ll = e & 63;
      float v = Wj[d * LP + l0 + ll];
      if (j > 0) v -= Wj[-(int)WSZ + d * LP + l0 + ll];
      D[d][ll] = v;
    }
  } else {
    for (int e = tid; e < 48 * 64; e += 256) { int d = e >> 6, ll = e & 63; D[d][ll] = 0.f; }
  }
  __syncthreads();
  for (int e = tid; e < 48 * 64; e += 256) {
    int ll = e / 48, d = e - ll * 48;
    KDT[(size_t)(l0 + ll) * KCV + j * 48 + d] = f2b(D[d][ll]);
  }
  __syncthreads();
}

__global__ __launch_bounds__(256, 2) void mega(const float* __restrict__ xs,
                                               const float* __restrict__ ts,
                                               const float* __restrict__ th0,
                                               const float* __restrict__ A,
                                               const float* __restrict__ B,
                                               float* __restrict__ ws,
                                               float* __restrict__ out) {
  __shared__ __align__(16) unsigned char smemRaw[36864];
  ushort (*As)[72] = (ushort(*)[72])smemRaw;             // 128 rows (2 bufs x 64)
  ushort (*Bs)[72] = (ushort(*)[72])(smemRaw + 18432);
  const int tid = threadIdx.x;
  const int bid = blockIdx.x;
  const int nb  = gridDim.x;

  ushort* EP = (ushort*)(ws + OFF_E);
  const size_t PL = (size_t)LP * LP;
  ushort* EN[6]; ushort* ET[5];
#pragma unroll
  for (int i = 0; i < 5; ++i) { EN[i] = EP + (size_t)(2 * i) * PL; ET[i] = EP + (size_t)(2 * i + 1) * PL; }
  EN[5] = EP + 10 * PL;
  float*  WF   = ws + OFF_WF;
  ushort* WB   = (ushort*)(ws + OFF_WB);
  ushort* KDT  = (ushort*)(ws + OFF_KDT);
  ushort* U    = (ushort*)(ws + OFF_U);
  float*  part = ws + OFF_PART;
  uint*   bar  = (uint*)(ws + OFF_BAR);
  uint    barid = 0;
  float cp[6];
  cp[0] = 0.99f;
#pragma unroll
  for (int i = 1; i < 6; ++i) cp[i] = cp[i - 1] * cp[i - 1];

  // ================= P0: prep (E1: 196 | W0: 14 | U: 192) =================
  for (int task = bid; task < 402; task += nb) {
    if (task < 196) {
      float (*T)[65] = (float(*)[65])smemRaw;
      const int bi = (task / 14) * 64, bj = (task % 14) * 64;
      const int r = tid >> 2, c0 = (tid & 3) * 16;
      const int gi = bi + r;
      __syncthreads();
#pragma unroll
      for (int q = 0; q < 4; ++q) {
        int c = c0 + q * 4, gj = bj + c;
        float4 v = {0.f, 0.f, 0.f, 0.f};
        if (gi < L && gj + 3 < L) {
          v = *(const float4*)(A + (size_t)gi * L + gj);
        } else if (gi < L) {
          if (gj + 0 < L) v.x = A[(size_t)gi * L + gj];
          if (gj + 1 < L) v.y = A[(size_t)gi * L + gj + 1];
          if (gj + 2 < L) v.z = A[(size_t)gi * L + gj + 2];
          if (gj + 3 < L) v.w = A[(size_t)gi * L + gj + 3];
        }
        if (gi == gj)     v.x -= 0.99f;
        if (gi == gj + 1) v.y -= 0.99f;
        if (gi == gj + 2) v.z -= 0.99f;
        if (gi == gj + 3) v.w -= 0.99f;
        T[r][c] = v.x; T[r][c + 1] = v.y; T[r][c + 2] = v.z; T[r][c + 3] = v.w;
      }
      __syncthreads();
      {
        union { ushort s[16]; u32x4 v[2]; } pk;
#pragma unroll
        for (int i = 0; i < 16; ++i) pk.s[i] = f2b(T[r][c0 + i]);
        *(u32x4*)(EN[0] + (size_t)(bi + r) * LP + bj + c0)     = pk.v[0];
        *(u32x4*)(EN[0] + (size_t)(bi + r) * LP + bj + c0 + 8) = pk.v[1];
      }
      {
        union { ushort s[16]; u32x4 v[2]; } pk;
#pragma unroll
        for (int i = 0; i < 16; ++i) pk.s[i] = f2b(T[c0 + i][r]);
        *(u32x4*)(ET[0] + (size_t)(bj + r) * LP + bi + c0)     = pk.v[0];
        *(u32x4*)(ET[0] + (size_t)(bj + r) * LP + bi + c0 + 8) = pk.v[1];
      }
      __syncthreads();
    } else if (task < 210) {
      int base = (task - 196) * 4096;
      for (int e = tid; e < 4096; e += 256) {
        int idx = base + e;
        int c = idx / LP, l = idx % LP;
        float v = 0.f;
        if (l < L) {
          if (c < DS) v = B[l * DS + c];
          else if (c == DS) v = th0[l];
          else if (c < 53) {
            int b = c - 49;
            float s = 0.f;
            for (int d = 0; d < DS; ++d) s += B[l * DS + d] * xs[(b * 64) * DS + d];
            v = -s;
          }
        }
        WF[idx] = v;
        WB[idx] = f2b(v);
      }
    } else {
      int idx0 = ((task - 210) * 256 + tid) * 16;   // 192 tasks cover 256*KCV
      int rr = idx0 / KCV, k = idx0 % KCV;
      u32x4 o0 = {}, o1 = {};
      if (rr < 252 && k < 3024) {
        int b = rr / 63, tau = rr - b * 63;
        int j = k / DS, d0 = k - j * DS;            // d0 in {0,16,32}
        int s = tau - j; if (s < 0) s += 63;
        const float* xp = xs + (size_t)(b * 64 + s + 1) * DS + d0;
        union { ushort u[16]; u32x4 v[2]; } pk;
#pragma unroll
        for (int q = 0; q < 16; ++q) pk.u[q] = f2b(xp[q]);
        o0 = pk.v[0]; o1 = pk.v[1];
      }
      *(u32x4*)(U + idx0)     = o0;
      *(u32x4*)(U + idx0 + 8) = o1;
    }
  }
  gbar(bar, ++barid);

  // ====== P1..P5: [sq E_S -> E_2S] || [chain W_{t+S} = c_S W_t + W_t E_S] ======
  for (int lev = 0; lev < 5; ++lev) {
    const int S = 1 << lev;
    const int ntask = 196 + S * 14;
    const float csq = 2.f * cp[lev];
    const float cch = cp[lev];
    for (int task = bid; task < ntask; task += nb) {
      f32x4 acc[2][2];
      const int wv = tid >> 6, lane = tid & 63;
      const int wm = (wv >> 1) * 32, wn = (wv & 1) * 32;
      const int lr = lane & 15, lg = lane >> 4;
      if (task < 196) {
        const int m0 = (task / 14) * 64, n0 = (task % 14) * 64;
        gemm64(EN[lev], ET[lev], LP, 14, 0, m0, n0, tid, As, Bs, acc);
        ushort (*T)[72] = As;
        __syncthreads();
#pragma unroll
        for (int fm = 0; fm < 2; ++fm)
#pragma unroll
          for (int fn = 0; fn < 2; ++fn)
#pragma unroll
            for (int rr = 0; rr < 4; ++rr) {
              int mi = wm + fm * 16 + lg * 4 + rr;
              int ni = wn + fn * 16 + lr;
              float v = acc[fm][fn][rr] + csq * b2f(EN[lev][(size_t)(m0 + mi) * LP + n0 + ni]);
              ushort bv = f2b(v);
              EN[lev + 1][(size_t)(m0 + mi) * LP + n0 + ni] = bv;
              T[ni][mi] = bv;
            }
        if (lev < 4) {
          __syncthreads();
          const int nr = tid >> 2, ct0 = (tid & 3) * 16;
          u32x4 o0 = *(const u32x4*)&T[nr][ct0];
          u32x4 o1 = *(const u32x4*)&T[nr][ct0 + 8];
          *(u32x4*)(ET[lev + 1] + (size_t)(n0 + nr) * LP + m0 + ct0)     = o0;
          *(u32x4*)(ET[lev + 1] + (size_t)(n0 + nr) * LP + m0 + ct0 + 8) = o1;
        }
        __syncthreads();
      } else {
        const int ct = task - 196;
        const int t = ct / 14, n0 = (ct % 14) * 64;
        gemm64(WB + (size_t)t * WSZ, EN[lev], LP, 14, 0, 0, n0, tid, As, Bs, acc);
        const size_t srcO = (size_t)t * WSZ, dstO = (size_t)(t + S) * WSZ;
#pragma unroll
        for (int fm = 0; fm < 2; ++fm)
#pragma unroll
          for (int fn = 0; fn < 2; ++fn)
#pragma unroll
            for (int rr = 0; rr < 4; ++rr) {
              int mi = wm + fm * 16 + lg * 4 + rr;
              int ni = n0 + wn + fn * 16 + lr;
              float v = acc[fm][fn][rr] + cch * WF[srcO + (size_t)mi * LP + ni];
              WF[dstO + (size_t)mi * LP + ni] = v;
              WB[dstO + (size_t)mi * LP + ni] = f2b(v);
            }
      }
    }
    gbar(bar, ++barid);
  }

  // ================= P6: L6 chain W32..63 (448) || kd j=0..31 (448) =================
  for (int task = bid; task < 896; task += nb) {
    if (task < 448) {
      f32x4 acc[2][2];
      const int wv = tid >> 6, lane = tid & 63;
      const int wm = (wv >> 1) * 32, wn = (wv & 1) * 32;
      const int lr = lane & 15, lg = lane >> 4;
      const int t = task / 14, n0 = (task % 14) * 64;
      gemm64(WB + (size_t)t * WSZ, EN[5], LP, 14, 0, 0, n0, tid, As, Bs, acc);
      const size_t srcO = (size_t)t * WSZ, dstO = (size_t)(t + 32) * WSZ;
#pragma unroll
      for (int fm = 0; fm < 2; ++fm)
#pragma unroll
        for (int fn = 0; fn < 2; ++fn)
#pragma unroll
          for (int rr = 0; rr < 4; ++rr) {
            int mi = wm + fm * 16 + lg * 4 + rr;
            int ni = n0 + wn + fn * 16 + lr;
            float v = acc[fm][fn][rr] + cp[5] * WF[srcO + (size_t)mi * LP + ni];
            WF[dstO + (size_t)mi * LP + ni] = v;
            WB[dstO + (size_t)mi * LP + ni] = f2b(v);
          }
    } else {
      int j = (task - 448) / 14, l0 = ((task - 448) % 14) * 64;
      kd_body(WF, KDT, j, l0, tid, (float(*)[65])smemRaw);
    }
  }
  gbar(bar, ++barid);

  // ================= P7: kd j=32..63 =================
  for (int task = bid; task < 448; task += nb) {
    int j = 32 + task / 14, l0 = (task % 14) * 64;
    kd_body(WF, KDT, j, l0, tid, (float(*)[65])smemRaw);
  }
  gbar(bar, ++barid);

  // ================= P8: conv part[z] = U . KDT^T (chunked K) =================
  for (int task = bid; task < 56 * NZ; task += nb) {
    f32x4 acc[2][2];
    const int wv = tid >> 6, lane = tid & 63;
    const int wm = (wv >> 1) * 32, wn = (wv & 1) * 32;
    const int lr = lane & 15, lg = lane >> 4;
    const int z = task / 56, rem = task % 56;
    const int m0 = (rem / 14) * 64, n0 = (rem % 14) * 64;
    gemm64(U, KDT, KCV, 16, z * 1024, m0, n0, tid, As, Bs, acc);
    float* pp = part + (size_t)z * (256 * LP);
#pragma unroll
    for (int fm = 0; fm < 2; ++fm)
#pragma unroll
      for (int fn = 0; fn < 2; ++fn)
#pragma unroll
        for (int rr = 0; rr < 4; ++rr) {
          int m = m0 + wm + fm * 16 + lg * 4 + rr;
          int n = n0 + wn + fn * 16 + lr;
          pp[(size_t)m * LP + n] = acc[fm][fn][rr];
        }
  }
  gbar(bar, ++barid);

  // ================= P9: assemble theta row in LDS + decode =================
  for (int task = bid; task < 256; task += nb) {
    float* th = (float*)smemRaw;
    const int bt = task, b = bt >> 6, t = bt & 63;
    __syncthreads();
    for (int l = tid; l < LP; l += 256) {
      float v = 0.f;
      if (l < L) {
        if (t == 0) v = th0[l];
        else {
          int rr = b * 63 + (t - 1);
          v = part[(size_t)rr * LP + l]
            + part[(size_t)(256 * LP) + rr * LP + l]
            + part[(size_t)(2 * 256 * LP) + rr * LP + l];
          int tau = t - 1;
          v += WF[(size_t)tau * WSZ + DS * LP + l];
          int tw = (tau + 62) % 63;
          v += WF[(size_t)tw * WSZ + (49 + b) * LP + l];
        }
      }
      th[l] = v;
    }
    __syncthreads();
    if (tid < OUTD) {
      int o = tid;
      float tv = ts[bt];
      float acc = th[784 + o];
#pragma unroll
      for (int i = 0; i < 8; ++i) {
        float h = fmaxf(th[i] * tv + th[8 + i], 0.f);
        acc += th[16 + o * 8 + i] * h;
      }
      float rs;
      if (o < DS) rs = tanhf(acc);
      else        rs = fmaxf(acc, 0.f) + log1pf(expf(-fabsf(acc)));
      out[bt * OUTD + o] = rs;
    }
    __syncthreads();
  }
}

extern "C" void kernel_launch(void* const* d_in, const int* in_sizes, int n_in,
                              void* d_out, int out_size, void* d_ws, size_t ws_size,
                              hipStream_t stream) {
  const float* xs  = (const float*)d_in[0];
  const float* ts  = (const float*)d_in[1];
  const float* th0 = (const float*)d_in[2];
  const float* A   = (const float*)d_in[3];
  const float* B   = (const float*)d_in[4];
  float* ws  = (float*)d_ws;
  float* out = (float*)d_out;

  k_init<<<1, 64, 0, stream>>>((uint*)(ws + OFF_BAR));
  mega<<<NBLK, 256, 0, stream>>>(xs, ts, th0, A, B, ws, out);
}

// Round 9
// 112.739 us; speedup vs baseline: 7.5203x; 7.5203x over previous
//
#include <hip/hip_runtime.h>
#include <math.h>

typedef unsigned int uint;
typedef unsigned short ushort;
typedef short s16x8 __attribute__((ext_vector_type(8)));
typedef float f32x4 __attribute__((ext_vector_type(4)));
typedef uint u32x4 __attribute__((ext_vector_type(4)));

#define L     880
#define LP    896
#define NC    64
#define WSZ   (NC * LP)
#define DS    48
#define OUTD  96
#define KCV   3072
#define NZ    6

// ws layout (float offsets). 11 bf16 E planes (401408 floats each) at 0.
// KDT (bf16, LP*KCV = 2752512 shorts) OVERLAYS planes 0..3.5 (EN1/ET1/EN2/ET2),
// which are dead by the time kd runs (after L5). EN32 = plane 10, untouched.
#define OFF_E    0
#define OFF_KDT  0
#define OFF_WF   4415488                    // 63 slabs f32
#define OFF_WB   (OFF_WF + 63 * WSZ)        // 63 slabs bf16
#define OFF_U    (OFF_WB + 63 * WSZ / 2)    // 256x3072 bf16
#define OFF_PART (OFF_U + 256 * KCV / 2)    // NZ x 256 x 896 f32
// total = OFF_PART + NZ*256*LP = 11603968 floats = 46.4 MiB

__device__ inline ushort f2b(float f) {
  uint u = __builtin_bit_cast(uint, f);
  u += 0x7fffu + ((u >> 16) & 1u);
  return (ushort)(u >> 16);
}
__device__ inline float b2f(ushort b) {
  uint u = ((uint)b) << 16;
  return __builtin_bit_cast(float, u);
}

// ---- 64x64xK GEMM core, 2-phase pipelined: reads(cur) -> writes(nxt) -> MFMA -> bar ----
// C[m][n] = sum_k Ag[m][k]*Bg[n][k]; BK=64; 4 waves 2x2 over 64x64; 16x16x32 bf16 MFMA.
__device__ __forceinline__ void gemm64(const ushort* __restrict__ Ag,
                                       const ushort* __restrict__ Bg,
                                       int Kdim, int kIters, int kOff, int m0, int n0,
                                       int tid, ushort (*As)[72], ushort (*Bs)[72],
                                       f32x4 acc[2][2]) {
  const int r = tid >> 2, kq = (tid & 3) * 16;
  const ushort* aptr = Ag + (size_t)(m0 + r) * Kdim + kOff + kq;
  const ushort* bptr = Bg + (size_t)(n0 + r) * Kdim + kOff + kq;
  const int wv = tid >> 6, lane = tid & 63;
  const int wm = (wv >> 1) * 32, wn = (wv & 1) * 32;
  const int lr = lane & 15, lg = lane >> 4;
  acc[0][0] = f32x4{0.f, 0.f, 0.f, 0.f};
  acc[0][1] = f32x4{0.f, 0.f, 0.f, 0.f};
  acc[1][0] = f32x4{0.f, 0.f, 0.f, 0.f};
  acc[1][1] = f32x4{0.f, 0.f, 0.f, 0.f};
  u32x4 ra0 = *(const u32x4*)aptr;
  u32x4 ra1 = *(const u32x4*)(aptr + 8);
  u32x4 rb0 = *(const u32x4*)bptr;
  u32x4 rb1 = *(const u32x4*)(bptr + 8);
  __syncthreads();                       // LDS reuse guard vs previous task
  *(u32x4*)&As[r][kq]     = ra0;
  *(u32x4*)&As[r][kq + 8] = ra1;
  *(u32x4*)&Bs[r][kq]     = rb0;
  *(u32x4*)&Bs[r][kq + 8] = rb1;
  if (kIters > 1) {
    ra0 = *(const u32x4*)(aptr + 64);
    ra1 = *(const u32x4*)(aptr + 72);
    rb0 = *(const u32x4*)(bptr + 64);
    rb1 = *(const u32x4*)(bptr + 72);
  }
  __syncthreads();                       // stage(0) visible
  for (int it = 0; it < kIters; ++it) {
    const int cur = (it & 1) * 64, nxt = cur ^ 64;
    s16x8 fa0[2], fa1[2], fb0[2], fb1[2];
#pragma unroll
    for (int k2 = 0; k2 < 2; ++k2) {
      fa0[k2] = *(const s16x8*)&As[cur + wm + lr][k2 * 32 + lg * 8];
      fa1[k2] = *(const s16x8*)&As[cur + wm + 16 + lr][k2 * 32 + lg * 8];
      fb0[k2] = *(const s16x8*)&Bs[cur + wn + lr][k2 * 32 + lg * 8];
      fb1[k2] = *(const s16x8*)&Bs[cur + wn + 16 + lr][k2 * 32 + lg * 8];
    }
    if (it + 1 < kIters) {               // stage next tile (other buffer) under MFMA wait
      *(u32x4*)&As[nxt + r][kq]     = ra0;
      *(u32x4*)&As[nxt + r][kq + 8] = ra1;
      *(u32x4*)&Bs[nxt + r][kq]     = rb0;
      *(u32x4*)&Bs[nxt + r][kq + 8] = rb1;
      if (it + 2 < kIters) {
        ra0 = *(const u32x4*)(aptr + (it + 2) * 64);
        ra1 = *(const u32x4*)(aptr + (it + 2) * 64 + 8);
        rb0 = *(const u32x4*)(bptr + (it + 2) * 64);
        rb1 = *(const u32x4*)(bptr + (it + 2) * 64 + 8);
      }
    }
#pragma unroll
    for (int k2 = 0; k2 < 2; ++k2) {
      acc[0][0] = __builtin_amdgcn_mfma_f32_16x16x32_bf16(fa0[k2], fb0[k2], acc[0][0], 0, 0, 0);
      acc[0][1] = __builtin_amdgcn_mfma_f32_16x16x32_bf16(fa0[k2], fb1[k2], acc[0][1], 0, 0, 0);
      acc[1][0] = __builtin_amdgcn_mfma_f32_16x16x32_bf16(fa1[k2], fb0[k2], acc[1][0], 0, 0, 0);
      acc[1][1] = __builtin_amdgcn_mfma_f32_16x16x32_bf16(fa1[k2], fb1[k2], acc[1][1], 0, 0, 0);
    }
    __syncthreads();
  }
}

// ---- kd task: KDT[l0..+63][j*48+d] = W_j[d][l] - W_{j-1}[d][l] (j=63 -> zero pad) ----
__device__ __forceinline__ void kd_body(const float* __restrict__ WF, ushort* __restrict__ KDT,
                                        int j, int l0, int tid, float (*D)[65]) {
  __syncthreads();
  if (j < 63) {
    const float* Wj = WF + (size_t)j * WSZ;
    for (int e = tid; e < 48 * 64; e += 256) {
      int d = e >> 6, ll = e & 63;
      float v = Wj[d * LP + l0 + ll];
      if (j > 0) v -= Wj[-(int)WSZ + d * LP + l0 + ll];
      D[d][ll] = v;
    }
  } else {
    for (int e = tid; e < 48 * 64; e += 256) { int d = e >> 6, ll = e & 63; D[d][ll] = 0.f; }
  }
  __syncthreads();
  for (int e = tid; e < 48 * 64; e += 256) {
    int ll = e / 48, d = e - ll * 48;
    KDT[(size_t)(l0 + ll) * KCV + j * 48 + d] = f2b(D[d][ll]);
  }
}

// ================= fused prep: E1(N+T) | W0 | U =================
__global__ __launch_bounds__(256) void k_prep(const float* __restrict__ A,
                                              const float* __restrict__ B,
                                              const float* __restrict__ th0,
                                              const float* __restrict__ xs,
                                              ushort* __restrict__ EN,
                                              ushort* __restrict__ ET,
                                              float* __restrict__ WF,
                                              ushort* __restrict__ WB,
                                              ushort* __restrict__ U) {
  const int blk = blockIdx.x;
  const int tid = threadIdx.x;
  if (blk < 196) {                       // ---- E1 = A - 0.99I, 64x64 tile ----
    __shared__ float T[64][65];
    const int bi = (blk / 14) * 64, bj = (blk % 14) * 64;
    const int r = tid >> 2, c0 = (tid & 3) * 16;
    const int gi = bi + r;
#pragma unroll
    for (int q = 0; q < 4; ++q) {
      int c = c0 + q * 4, gj = bj + c;
      float4 v = {0.f, 0.f, 0.f, 0.f};
      if (gi < L && gj + 3 < L) {
        v = *(const float4*)(A + (size_t)gi * L + gj);
      } else if (gi < L) {
        if (gj + 0 < L) v.x = A[(size_t)gi * L + gj];
        if (gj + 1 < L) v.y = A[(size_t)gi * L + gj + 1];
        if (gj + 2 < L) v.z = A[(size_t)gi * L + gj + 2];
        if (gj + 3 < L) v.w = A[(size_t)gi * L + gj + 3];
      }
      if (gi == gj)     v.x -= 0.99f;
      if (gi == gj + 1) v.y -= 0.99f;
      if (gi == gj + 2) v.z -= 0.99f;
      if (gi == gj + 3) v.w -= 0.99f;
      T[r][c] = v.x; T[r][c + 1] = v.y; T[r][c + 2] = v.z; T[r][c + 3] = v.w;
    }
    __syncthreads();
    {
      union { ushort s[16]; u32x4 v[2]; } pk;
#pragma unroll
      for (int i = 0; i < 16; ++i) pk.s[i] = f2b(T[r][c0 + i]);
      *(u32x4*)(EN + (size_t)(bi + r) * LP + bj + c0)     = pk.v[0];
      *(u32x4*)(EN + (size_t)(bi + r) * LP + bj + c0 + 8) = pk.v[1];
    }
    {
      union { ushort s[16]; u32x4 v[2]; } pk;
#pragma unroll
      for (int i = 0; i < 16; ++i) pk.s[i] = f2b(T[c0 + i][r]);
      *(u32x4*)(ET + (size_t)(bj + r) * LP + bi + c0)     = pk.v[0];
      *(u32x4*)(ET + (size_t)(bj + r) * LP + bi + c0 + 8) = pk.v[1];
    }
  } else if (blk < 210) {                // ---- W0 slab ----
    int base = (blk - 196) * 4096;
    for (int e = tid; e < 4096; e += 256) {
      int idx = base + e;
      int c = idx / LP, l = idx % LP;
      float v = 0.f;
      if (l < L) {
        if (c < DS) v = B[l * DS + c];
        else if (c == DS) v = th0[l];
        else if (c < 53) {
          int b = c - 49;
          float s = 0.f;
          for (int d = 0; d < DS; ++d) s += B[l * DS + d] * xs[(b * 64) * DS + d];
          v = -s;
        }
      }
      WF[idx] = v;
      WB[idx] = f2b(v);
    }
  } else {                               // ---- U gather (bf16, 4/thread) ----
    int idx = ((blk - 210) * 256 + tid) * 4;   // 768 blocks cover 256*KCV
    int rr = idx / KCV, k = idx - rr * KCV;
    ushort4 v = {0, 0, 0, 0};
    if (rr < 252 && k < 3024) {
      int b = rr / 63, tau = rr - b * 63;
      int j = k / DS, d = k - j * DS;
      int s = tau - j; if (s < 0) s += 63;
      float4 x4 = *(const float4*)(xs + (size_t)(b * 64 + s + 1) * DS + d);
      v.x = f2b(x4.x); v.y = f2b(x4.y); v.z = f2b(x4.z); v.w = f2b(x4.w);
    }
    *(ushort4*)(U + idx) = v;
  }
}

// ================= ladder: [sq | chain | kd] by blockIdx.y =================
__global__ __launch_bounds__(256) void k_ladder(
    const ushort* __restrict__ sqA, const ushort* __restrict__ sqBT, float cs2,
    ushort* __restrict__ sqOutN, ushort* __restrict__ sqOutT, int ySq,
    int nCh, const ushort* __restrict__ chWB, const ushort* __restrict__ chE, float csc,
    const float* __restrict__ chWFsrc, float* __restrict__ chWFdst,
    ushort* __restrict__ chWBdst,
    int kdJ0, const float* __restrict__ kdWF, ushort* __restrict__ kdKDT) {
  __shared__ __align__(16) ushort As[128][72];
  __shared__ __align__(16) ushort Bs[128][72];
  const int tid = threadIdx.x;
  const int y = blockIdx.y;
  const int n0 = blockIdx.x * 64;
  const int wv = tid >> 6, lane = tid & 63;
  const int wm = (wv >> 1) * 32, wn = (wv & 1) * 32;
  const int lr = lane & 15, lg = lane >> 4;

  if (y < ySq) {                         // ---- square: E_2S = E_S^2 + cs2*E_S ----
    const int m0 = y * 64;
    f32x4 acc[2][2];
    gemm64(sqA, sqBT, LP, LP / 64, 0, m0, n0, tid, As, Bs, acc);
    ushort (*T)[72] = As;
#pragma unroll
    for (int fm = 0; fm < 2; ++fm)
#pragma unroll
      for (int fn = 0; fn < 2; ++fn)
#pragma unroll
        for (int rr = 0; rr < 4; ++rr) {
          int mi = wm + fm * 16 + lg * 4 + rr;
          int ni = wn + fn * 16 + lr;
          float v = acc[fm][fn][rr] + cs2 * b2f(sqA[(size_t)(m0 + mi) * LP + n0 + ni]);
          ushort bv = f2b(v);
          sqOutN[(size_t)(m0 + mi) * LP + n0 + ni] = bv;
          T[ni][mi] = bv;
        }
    if (sqOutT) {
      __syncthreads();
      const int nr = tid >> 2, ct0 = (tid & 3) * 16;
      u32x4 o0 = *(const u32x4*)&T[nr][ct0];
      u32x4 o1 = *(const u32x4*)&T[nr][ct0 + 8];
      *(u32x4*)(sqOutT + (size_t)(n0 + nr) * LP + m0 + ct0)     = o0;
      *(u32x4*)(sqOutT + (size_t)(n0 + nr) * LP + m0 + ct0 + 8) = o1;
    }
  } else if (y < ySq + nCh) {            // ---- chain: W_dst = csc*W_src + W_src.E ----
    const int t = y - ySq;
    f32x4 acc[2][2];
    gemm64(chWB + (size_t)t * WSZ, chE, LP, LP / 64, 0, 0, n0, tid, As, Bs, acc);
    const float*  srcF = chWFsrc + (size_t)t * WSZ;
    float*        dstF = chWFdst + (size_t)t * WSZ;
    ushort*       dstB = chWBdst + (size_t)t * WSZ;
#pragma unroll
    for (int fm = 0; fm < 2; ++fm)
#pragma unroll
      for (int fn = 0; fn < 2; ++fn)
#pragma unroll
        for (int rr = 0; rr < 4; ++rr) {
          int mi = wm + fm * 16 + lg * 4 + rr;
          int ni = n0 + wn + fn * 16 + lr;
          float v = acc[fm][fn][rr] + csc * srcF[(size_t)mi * LP + ni];
          dstF[(size_t)mi * LP + ni] = v;
          dstB[(size_t)mi * LP + ni] = f2b(v);
        }
  } else {                               // ---- kd ----
    int j = kdJ0 + (y - ySq - nCh);
    kd_body(kdWF, kdKDT, j, n0, tid, (float(*)[65])As);
  }
}

// ================= standalone kd (j = j0 + blockIdx.y) =================
__global__ __launch_bounds__(256) void k_kd(const float* __restrict__ WF,
                                            ushort* __restrict__ KDT, int j0) {
  __shared__ float D[48][65];
  kd_body(WF, KDT, j0 + blockIdx.y, blockIdx.x * 64, threadIdx.x, D);
}

// ================= conv GEMM: part[z][r][l] = sum_{k in chunk z} U[r][k]*KDT[l][k] ======
__global__ __launch_bounds__(256) void k_conv(const ushort* __restrict__ U,
                                              const ushort* __restrict__ KDT,
                                              float* __restrict__ part) {
  __shared__ __align__(16) ushort As[128][72];
  __shared__ __align__(16) ushort Bs[128][72];
  const int tid = threadIdx.x;
  const int n0 = blockIdx.x * 64, m0 = blockIdx.y * 64;
  const int kOff = blockIdx.z * (KCV / NZ);
  const int wv = tid >> 6, lane = tid & 63;
  const int wm = (wv >> 1) * 32, wn = (wv & 1) * 32;
  const int lr = lane & 15, lg = lane >> 4;
  f32x4 acc[2][2];
  gemm64(U, KDT, KCV, (KCV / NZ) / 64, kOff, m0, n0, tid, As, Bs, acc);
  float* pp = part + (size_t)blockIdx.z * (256 * LP);
#pragma unroll
  for (int fm = 0; fm < 2; ++fm)
#pragma unroll
    for (int fn = 0; fn < 2; ++fn)
#pragma unroll
      for (int rr = 0; rr < 4; ++rr) {
        int m = m0 + wm + fm * 16 + lg * 4 + rr;
        int n = n0 + wn + fn * 16 + lr;
        pp[(size_t)m * LP + n] = acc[fm][fn][rr];
      }
}

// ================= final: assemble theta row in LDS, decode =================
__global__ __launch_bounds__(256) void k_final(const float* __restrict__ part,
                                               const float* __restrict__ WF,
                                               const float* __restrict__ th0,
                                               const float* __restrict__ ts,
                                               float* __restrict__ out) {
  __shared__ float th[LP];
  const int bt = blockIdx.x, b = bt >> 6, t = bt & 63;
  for (int l = threadIdx.x; l < LP; l += 256) {
    float v = 0.f;
    if (l < L) {
      if (t == 0) v = th0[l];
      else {
        int rr = b * 63 + (t - 1);
        v = 0.f;
#pragma unroll
        for (int z = 0; z < NZ; ++z) v += part[(size_t)z * (256 * LP) + rr * LP + l];
        int tau = t - 1;
        v += WF[(size_t)tau * WSZ + DS * LP + l];       // A^tau @ theta0
        int tw = (tau + 62) % 63;
        v += WF[(size_t)tw * WSZ + (49 + b) * LP + l];  // A^{(tau-1)%63} @ sig1_b
      }
    }
    th[l] = v;
  }
  __syncthreads();
  int o = threadIdx.x;
  if (o < OUTD) {
    float tv = ts[bt];
    float acc = th[784 + o];
#pragma unroll
    for (int i = 0; i < 8; ++i) {
      float h = fmaxf(th[i] * tv + th[8 + i], 0.f);
      acc += th[16 + o * 8 + i] * h;
    }
    float rs;
    if (o < DS) rs = tanhf(acc);
    else        rs = fmaxf(acc, 0.f) + log1pf(expf(-fabsf(acc)));
    out[bt * OUTD + o] = rs;
  }
}

extern "C" void kernel_launch(void* const* d_in, const int* in_sizes, int n_in,
                              void* d_out, int out_size, void* d_ws, size_t ws_size,
                              hipStream_t stream) {
  const float* xs  = (const float*)d_in[0];
  const float* ts  = (const float*)d_in[1];
  const float* th0 = (const float*)d_in[2];
  const float* A   = (const float*)d_in[3];
  const float* B   = (const float*)d_in[4];
  float* out = (float*)d_out;
  float* ws  = (float*)d_ws;

  ushort* EP   = (ushort*)(ws + OFF_E);
  const size_t PL = (size_t)LP * LP;
  ushort* EN1  = EP + 0 * PL;
  ushort* ET1  = EP + 1 * PL;
  ushort* EN2  = EP + 2 * PL;
  ushort* ET2  = EP + 3 * PL;
  ushort* EN4  = EP + 4 * PL;
  ushort* ET4  = EP + 5 * PL;
  ushort* EN8  = EP + 6 * PL;
  ushort* ET8  = EP + 7 * PL;
  ushort* EN16 = EP + 8 * PL;
  ushort* ET16 = EP + 9 * PL;
  ushort* EN32 = EP + 10 * PL;
  float*  WF   = ws + OFF_WF;
  ushort* WB   = (ushort*)(ws + OFF_WB);
  ushort* KDT  = (ushort*)(ws + OFF_KDT);   // overlays E planes 0..3 (dead after L5)
  ushort* U    = (ushort*)(ws + OFF_U);
  float*  part = ws + OFF_PART;

  const float c1 = 0.99f;
  const float c2 = c1 * c1, c4 = c2 * c2, c8 = c4 * c4, c16 = c8 * c8, c32 = c16 * c16;

  k_prep<<<978, 256, 0, stream>>>(A, B, th0, xs, EN1, ET1, WF, WB, U);

  // L1..L5: sq E_S -> E_2S (14 rows) || chain W_{t+S} = c_S*W_t + W_t.E_S (S rows)
  k_ladder<<<dim3(14, 15), 256, 0, stream>>>(EN1, ET1, 2.f * c1, EN2, ET2, 14,
                                             1, WB, EN1, c1, WF, WF + 1 * WSZ, WB + (size_t)1 * WSZ,
                                             0, nullptr, nullptr);
  k_ladder<<<dim3(14, 16), 256, 0, stream>>>(EN2, ET2, 2.f * c2, EN4, ET4, 14,
                                             2, WB, EN2, c2, WF, WF + 2 * WSZ, WB + (size_t)2 * WSZ,
                                             0, nullptr, nullptr);
  k_ladder<<<dim3(14, 18), 256, 0, stream>>>(EN4, ET4, 2.f * c4, EN8, ET8, 14,
                                             4, WB, EN4, c4, WF, WF + 4 * WSZ, WB + (size_t)4 * WSZ,
                                             0, nullptr, nullptr);
  k_ladder<<<dim3(14, 22), 256, 0, stream>>>(EN8, ET8, 2.f * c8, EN16, ET16, 14,
                                             8, WB, EN8, c8, WF, WF + 8 * WSZ, WB + (size_t)8 * WSZ,
                                             0, nullptr, nullptr);
  k_ladder<<<dim3(14, 30), 256, 0, stream>>>(EN16, ET16, 2.f * c16, EN32, nullptr, 14,
                                             16, WB, EN16, c16, WF, WF + 16 * WSZ, WB + (size_t)16 * WSZ,
                                             0, nullptr, nullptr);
  // L6: chain W32..62 (31 rows) || kd j=0..31 (32 rows)
  k_ladder<<<dim3(14, 63), 256, 0, stream>>>(nullptr, nullptr, 0.f, nullptr, nullptr, 0,
                                             31, WB, EN32, c32, WF, WF + 32 * WSZ, WB + (size_t)32 * WSZ,
                                             0, WF, KDT);
  // kd j=32..63 (63 -> zero pad)
  k_kd<<<dim3(14, 32), 256, 0, stream>>>(WF, KDT, 32);

  k_conv<<<dim3(14, 4, NZ), 256, 0, stream>>>(U, KDT, part);
  k_final<<<256, 256, 0, stream>>>(part, WF, th0, ts, out);
}

// Round 10
// 93.257 us; speedup vs baseline: 9.0913x; 1.2089x over previous
//
#include <hip/hip_runtime.h>
#include <math.h>

typedef unsigned int uint;
typedef unsigned short ushort;
typedef short s16x8 __attribute__((ext_vector_type(8)));
typedef float f32x4 __attribute__((ext_vector_type(4)));
typedef uint u32x4 __attribute__((ext_vector_type(4)));

#define L     880
#define LP    896
#define NC    64
#define WSZ   (NC * LP)
#define DS    48
#define OUTD  96
#define KCV   3072
#define NZ    6

// ws layout (float offsets). 11 bf16 E planes (401408 floats each) at 0.
// KDT (bf16, LP*KCV shorts) OVERLAYS planes 0..3.5 (EN1/ET1/EN2/ET2), dead after L5.
#define OFF_E    0
#define OFF_KDT  0
#define OFF_WF   4415488                    // 63 slabs f32
#define OFF_WB   (OFF_WF + 63 * WSZ)        // 63 slabs bf16
#define OFF_U    (OFF_WB + 63 * WSZ / 2)    // 256x3072 bf16
#define OFF_PART (OFF_U + 256 * KCV / 2)    // NZ x 256 x 896 f32
// total 11603968 floats = 46.4 MiB

// LDS geometry for the split-K GEMM: per group 2 dbuf x 64 rows x 72 pitch (ushort)
#define LROW   72
#define LBUF   (64 * LROW)        // 4608 ushorts per buffer
#define LGRP   (2 * LBUF)         // per-group area

__device__ inline ushort f2b(float f) {
  uint u = __builtin_bit_cast(uint, f);
  u += 0x7fffu + ((u >> 16) & 1u);
  return (ushort)(u >> 16);
}
__device__ inline float b2f(ushort b) {
  uint u = ((uint)b) << 16;
  return __builtin_bit_cast(float, u);
}

// ---- 64x64xK GEMM, in-block split-K over 2 wave-groups (512 threads) ----
// C[m][n] = sum_k Ag[m][k]*Bg[n][k]. Group g covers k-half g. After the loop,
// group 1 dumps acc to LDS (conflict-free layout), group 0 merges; epilogue is
// done by tid<256 using the same (wv,lane) mapping as the 256-thread version.
__device__ __forceinline__ void gemm64sk(const ushort* __restrict__ Ag,
                                         const ushort* __restrict__ Bg,
                                         int Kdim, int kIters, int kOff, int m0, int n0,
                                         int tid, ushort* ldsA, ushort* ldsB,
                                         f32x4 acc[2][2]) {
  const int grp = tid >> 8;
  const int t2  = tid & 255;
  const int KH  = kIters >> 1;                 // iters per group (kIters even)
  const int gL  = grp * LGRP;
  const int kOffG = kOff + grp * KH * 64;
  const int r = t2 >> 2, kq = (t2 & 3) * 16;
  const ushort* aptr = Ag + (size_t)(m0 + r) * Kdim + kOffG + kq;
  const ushort* bptr = Bg + (size_t)(n0 + r) * Kdim + kOffG + kq;
  const int wv = t2 >> 6, lane = tid & 63;
  const int wm = (wv >> 1) * 32, wn = (wv & 1) * 32;
  const int lr = lane & 15, lg = lane >> 4;
  acc[0][0] = f32x4{0.f, 0.f, 0.f, 0.f};
  acc[0][1] = f32x4{0.f, 0.f, 0.f, 0.f};
  acc[1][0] = f32x4{0.f, 0.f, 0.f, 0.f};
  acc[1][1] = f32x4{0.f, 0.f, 0.f, 0.f};
  u32x4 ra0 = *(const u32x4*)aptr;
  u32x4 ra1 = *(const u32x4*)(aptr + 8);
  u32x4 rb0 = *(const u32x4*)bptr;
  u32x4 rb1 = *(const u32x4*)(bptr + 8);
  __syncthreads();                             // LDS reuse guard
  *(u32x4*)&ldsA[gL + r * LROW + kq]     = ra0;
  *(u32x4*)&ldsA[gL + r * LROW + kq + 8] = ra1;
  *(u32x4*)&ldsB[gL + r * LROW + kq]     = rb0;
  *(u32x4*)&ldsB[gL + r * LROW + kq + 8] = rb1;
  if (KH > 1) {
    ra0 = *(const u32x4*)(aptr + 64);
    ra1 = *(const u32x4*)(aptr + 72);
    rb0 = *(const u32x4*)(bptr + 64);
    rb1 = *(const u32x4*)(bptr + 72);
  }
  __syncthreads();                             // stage(0) visible
  for (int it = 0; it < KH; ++it) {
    const int cur = gL + (it & 1) * LBUF;
    const int nxt = gL + ((it & 1) ^ 1) * LBUF;
    s16x8 fa0[2], fa1[2], fb0[2], fb1[2];
#pragma unroll
    for (int k2 = 0; k2 < 2; ++k2) {
      fa0[k2] = *(const s16x8*)&ldsA[cur + (wm + lr) * LROW + k2 * 32 + lg * 8];
      fa1[k2] = *(const s16x8*)&ldsA[cur + (wm + 16 + lr) * LROW + k2 * 32 + lg * 8];
      fb0[k2] = *(const s16x8*)&ldsB[cur + (wn + lr) * LROW + k2 * 32 + lg * 8];
      fb1[k2] = *(const s16x8*)&ldsB[cur + (wn + 16 + lr) * LROW + k2 * 32 + lg * 8];
    }
    if (it + 1 < KH) {                         // stage next under MFMA wait
      *(u32x4*)&ldsA[nxt + r * LROW + kq]     = ra0;
      *(u32x4*)&ldsA[nxt + r * LROW + kq + 8] = ra1;
      *(u32x4*)&ldsB[nxt + r * LROW + kq]     = rb0;
      *(u32x4*)&ldsB[nxt + r * LROW + kq + 8] = rb1;
      if (it + 2 < KH) {
        ra0 = *(const u32x4*)(aptr + (it + 2) * 64);
        ra1 = *(const u32x4*)(aptr + (it + 2) * 64 + 8);
        rb0 = *(const u32x4*)(bptr + (it + 2) * 64);
        rb1 = *(const u32x4*)(bptr + (it + 2) * 64 + 8);
      }
    }
#pragma unroll
    for (int k2 = 0; k2 < 2; ++k2) {
      acc[0][0] = __builtin_amdgcn_mfma_f32_16x16x32_bf16(fa0[k2], fb0[k2], acc[0][0], 0, 0, 0);
      acc[0][1] = __builtin_amdgcn_mfma_f32_16x16x32_bf16(fa0[k2], fb1[k2], acc[0][1], 0, 0, 0);
      acc[1][0] = __builtin_amdgcn_mfma_f32_16x16x32_bf16(fa1[k2], fb0[k2], acc[1][0], 0, 0, 0);
      acc[1][1] = __builtin_amdgcn_mfma_f32_16x16x32_bf16(fa1[k2], fb1[k2], acc[1][1], 0, 0, 0);
    }
    __syncthreads();
  }
  // ---- cross-group reduce: red[e*256 + t2] (conflict-free: consecutive lanes -> banks)
  float* red = (float*)ldsA;
  if (grp == 1) {
#pragma unroll
    for (int m = 0; m < 2; ++m)
#pragma unroll
      for (int n = 0; n < 2; ++n)
#pragma unroll
        for (int rr = 0; rr < 4; ++rr)
          red[((m * 2 + n) * 4 + rr) * 256 + t2] = acc[m][n][rr];
  }
  __syncthreads();
  if (grp == 0) {
#pragma unroll
    for (int m = 0; m < 2; ++m)
#pragma unroll
      for (int n = 0; n < 2; ++n)
#pragma unroll
        for (int rr = 0; rr < 4; ++rr)
          acc[m][n][rr] += red[((m * 2 + n) * 4 + rr) * 256 + t2];
  }
}

// ---- kd task (512 threads): KDT[l0..+63][j*48+d] = W_j[d][l]-W_{j-1}[d][l] (j=63 pad) ----
__device__ __forceinline__ void kd_body(const float* __restrict__ WF, ushort* __restrict__ KDT,
                                        int j, int l0, int tid, float (*D)[65]) {
  __syncthreads();
  if (j < 63) {
    const float* Wj = WF + (size_t)j * WSZ;
    for (int e = tid; e < 48 * 64; e += 512) {
      int d = e >> 6, ll = e & 63;
      float v = Wj[d * LP + l0 + ll];
      if (j > 0) v -= Wj[-(int)WSZ + d * LP + l0 + ll];
      D[d][ll] = v;
    }
  } else {
    for (int e = tid; e < 48 * 64; e += 512) { int d = e >> 6, ll = e & 63; D[d][ll] = 0.f; }
  }
  __syncthreads();
  for (int e = tid; e < 48 * 64; e += 512) {
    int ll = e / 48, d = e - ll * 48;
    KDT[(size_t)(l0 + ll) * KCV + j * 48 + d] = f2b(D[d][ll]);
  }
}

// ================= fused prep: E1(N+T) | W0 | U  (256 threads) =================
__global__ __launch_bounds__(256) void k_prep(const float* __restrict__ A,
                                              const float* __restrict__ B,
                                              const float* __restrict__ th0,
                                              const float* __restrict__ xs,
                                              ushort* __restrict__ EN,
                                              ushort* __restrict__ ET,
                                              float* __restrict__ WF,
                                              ushort* __restrict__ WB,
                                              ushort* __restrict__ U) {
  const int blk = blockIdx.x;
  const int tid = threadIdx.x;
  if (blk < 196) {
    __shared__ float T[64][65];
    const int bi = (blk / 14) * 64, bj = (blk % 14) * 64;
    const int r = tid >> 2, c0 = (tid & 3) * 16;
    const int gi = bi + r;
#pragma unroll
    for (int q = 0; q < 4; ++q) {
      int c = c0 + q * 4, gj = bj + c;
      float4 v = {0.f, 0.f, 0.f, 0.f};
      if (gi < L && gj + 3 < L) {
        v = *(const float4*)(A + (size_t)gi * L + gj);
      } else if (gi < L) {
        if (gj + 0 < L) v.x = A[(size_t)gi * L + gj];
        if (gj + 1 < L) v.y = A[(size_t)gi * L + gj + 1];
        if (gj + 2 < L) v.z = A[(size_t)gi * L + gj + 2];
        if (gj + 3 < L) v.w = A[(size_t)gi * L + gj + 3];
      }
      if (gi == gj)     v.x -= 0.99f;
      if (gi == gj + 1) v.y -= 0.99f;
      if (gi == gj + 2) v.z -= 0.99f;
      if (gi == gj + 3) v.w -= 0.99f;
      T[r][c] = v.x; T[r][c + 1] = v.y; T[r][c + 2] = v.z; T[r][c + 3] = v.w;
    }
    __syncthreads();
    {
      union { ushort s[16]; u32x4 v[2]; } pk;
#pragma unroll
      for (int i = 0; i < 16; ++i) pk.s[i] = f2b(T[r][c0 + i]);
      *(u32x4*)(EN + (size_t)(bi + r) * LP + bj + c0)     = pk.v[0];
      *(u32x4*)(EN + (size_t)(bi + r) * LP + bj + c0 + 8) = pk.v[1];
    }
    {
      union { ushort s[16]; u32x4 v[2]; } pk;
#pragma unroll
      for (int i = 0; i < 16; ++i) pk.s[i] = f2b(T[c0 + i][r]);
      *(u32x4*)(ET + (size_t)(bj + r) * LP + bi + c0)     = pk.v[0];
      *(u32x4*)(ET + (size_t)(bj + r) * LP + bi + c0 + 8) = pk.v[1];
    }
  } else if (blk < 210) {
    int base = (blk - 196) * 4096;
    for (int e = tid; e < 4096; e += 256) {
      int idx = base + e;
      int c = idx / LP, l = idx % LP;
      float v = 0.f;
      if (l < L) {
        if (c < DS) v = B[l * DS + c];
        else if (c == DS) v = th0[l];
        else if (c < 53) {
          int b = c - 49;
          float s = 0.f;
          for (int d = 0; d < DS; ++d) s += B[l * DS + d] * xs[(b * 64) * DS + d];
          v = -s;
        }
      }
      WF[idx] = v;
      WB[idx] = f2b(v);
    }
  } else {
    int idx = ((blk - 210) * 256 + tid) * 4;   // 768 blocks cover 256*KCV
    int rr = idx / KCV, k = idx - rr * KCV;
    ushort4 v = {0, 0, 0, 0};
    if (rr < 252 && k < 3024) {
      int b = rr / 63, tau = rr - b * 63;
      int j = k / DS, d = k - j * DS;
      int s = tau - j; if (s < 0) s += 63;
      float4 x4 = *(const float4*)(xs + (size_t)(b * 64 + s + 1) * DS + d);
      v.x = f2b(x4.x); v.y = f2b(x4.y); v.z = f2b(x4.z); v.w = f2b(x4.w);
    }
    *(ushort4*)(U + idx) = v;
  }
}

// ================= ladder (512 thr): [sq | chain | kd] by blockIdx.y =================
__global__ __launch_bounds__(512, 4) void k_ladder(
    const ushort* __restrict__ sqA, const ushort* __restrict__ sqBT, float cs2,
    ushort* __restrict__ sqOutN, ushort* __restrict__ sqOutT, int ySq,
    int nCh, const ushort* __restrict__ chWB, const ushort* __restrict__ chE, float csc,
    const float* __restrict__ chWFsrc, float* __restrict__ chWFdst,
    ushort* __restrict__ chWBdst,
    int kdJ0, const float* __restrict__ kdWF, ushort* __restrict__ kdKDT) {
  __shared__ __align__(16) ushort ldsA[2 * LGRP];
  __shared__ __align__(16) ushort ldsB[2 * LGRP];
  const int tid = threadIdx.x;
  const int y = blockIdx.y;
  const int n0 = blockIdx.x * 64;
  const int wv = (tid & 255) >> 6, lane = tid & 63;
  const int wm = (wv >> 1) * 32, wn = (wv & 1) * 32;
  const int lr = lane & 15, lg = lane >> 4;

  if (y < ySq) {                         // ---- square: E_2S = E_S^2 + cs2*E_S ----
    const int m0 = y * 64;
    f32x4 acc[2][2];
    gemm64sk(sqA, sqBT, LP, LP / 64, 0, m0, n0, tid, ldsA, ldsB, acc);
    ushort* T = ldsB;                    // [64][LROW] bounce, group-0 region
    if (tid < 256) {
#pragma unroll
      for (int fm = 0; fm < 2; ++fm)
#pragma unroll
        for (int fn = 0; fn < 2; ++fn)
#pragma unroll
          for (int rr = 0; rr < 4; ++rr) {
            int mi = wm + fm * 16 + lg * 4 + rr;
            int ni = wn + fn * 16 + lr;
            float v = acc[fm][fn][rr] + cs2 * b2f(sqA[(size_t)(m0 + mi) * LP + n0 + ni]);
            ushort bv = f2b(v);
            sqOutN[(size_t)(m0 + mi) * LP + n0 + ni] = bv;
            T[ni * LROW + mi] = bv;
          }
    }
    __syncthreads();
    if (sqOutT && tid < 256) {
      const int nr = tid >> 2, ct0 = (tid & 3) * 16;
      u32x4 o0 = *(const u32x4*)&T[nr * LROW + ct0];
      u32x4 o1 = *(const u32x4*)&T[nr * LROW + ct0 + 8];
      *(u32x4*)(sqOutT + (size_t)(n0 + nr) * LP + m0 + ct0)     = o0;
      *(u32x4*)(sqOutT + (size_t)(n0 + nr) * LP + m0 + ct0 + 8) = o1;
    }
  } else if (y < ySq + nCh) {            // ---- chain: W_dst = csc*W_src + W_src.E ----
    const int t = y - ySq;
    f32x4 acc[2][2];
    gemm64sk(chWB + (size_t)t * WSZ, chE, LP, LP / 64, 0, 0, n0, tid, ldsA, ldsB, acc);
    if (tid < 256) {
      const float*  srcF = chWFsrc + (size_t)t * WSZ;
      float*        dstF = chWFdst + (size_t)t * WSZ;
      ushort*       dstB = chWBdst + (size_t)t * WSZ;
#pragma unroll
      for (int fm = 0; fm < 2; ++fm)
#pragma unroll
        for (int fn = 0; fn < 2; ++fn)
#pragma unroll
          for (int rr = 0; rr < 4; ++rr) {
            int mi = wm + fm * 16 + lg * 4 + rr;
            int ni = n0 + wn + fn * 16 + lr;
            float v = acc[fm][fn][rr] + csc * srcF[(size_t)mi * LP + ni];
            dstF[(size_t)mi * LP + ni] = v;
            dstB[(size_t)mi * LP + ni] = f2b(v);
          }
    }
  } else {                               // ---- kd ----
    int j = kdJ0 + (y - ySq - nCh);
    kd_body(kdWF, kdKDT, j, n0, tid, (float(*)[65])ldsA);
  }
}

// ================= standalone kd (512 thr) =================
__global__ __launch_bounds__(512) void k_kd(const float* __restrict__ WF,
                                            ushort* __restrict__ KDT, int j0) {
  __shared__ float D[48][65];
  kd_body(WF, KDT, j0 + blockIdx.y, blockIdx.x * 64, threadIdx.x, D);
}

// ================= conv GEMM (512 thr): part[z][r][l] = sum_k U[r][k]*KDT[l][k] =========
__global__ __launch_bounds__(512, 4) void k_conv(const ushort* __restrict__ U,
                                                 const ushort* __restrict__ KDT,
                                                 float* __restrict__ part) {
  __shared__ __align__(16) ushort ldsA[2 * LGRP];
  __shared__ __align__(16) ushort ldsB[2 * LGRP];
  const int tid = threadIdx.x;
  const int n0 = blockIdx.x * 64, m0 = blockIdx.y * 64;
  const int kOff = blockIdx.z * (KCV / NZ);
  const int wv = (tid & 255) >> 6, lane = tid & 63;
  const int wm = (wv >> 1) * 32, wn = (wv & 1) * 32;
  const int lr = lane & 15, lg = lane >> 4;
  f32x4 acc[2][2];
  gemm64sk(U, KDT, KCV, (KCV / NZ) / 64, kOff, m0, n0, tid, ldsA, ldsB, acc);
  if (tid < 256) {
    float* pp = part + (size_t)blockIdx.z * (256 * LP);
#pragma unroll
    for (int fm = 0; fm < 2; ++fm)
#pragma unroll
      for (int fn = 0; fn < 2; ++fn)
#pragma unroll
        for (int rr = 0; rr < 4; ++rr) {
          int m = m0 + wm + fm * 16 + lg * 4 + rr;
          int n = n0 + wn + fn * 16 + lr;
          pp[(size_t)m * LP + n] = acc[fm][fn][rr];
        }
  }
}

// ================= final: assemble theta row in LDS, decode =================
__global__ __launch_bounds__(256) void k_final(const float* __restrict__ part,
                                               const float* __restrict__ WF,
                                               const float* __restrict__ th0,
                                               const float* __restrict__ ts,
                                               float* __restrict__ out) {
  __shared__ float th[LP];
  const int bt = blockIdx.x, b = bt >> 6, t = bt & 63;
  for (int l = threadIdx.x; l < LP; l += 256) {
    float v = 0.f;
    if (l < L) {
      if (t == 0) v = th0[l];
      else {
        int rr = b * 63 + (t - 1);
        v = 0.f;
#pragma unroll
        for (int z = 0; z < NZ; ++z) v += part[(size_t)z * (256 * LP) + rr * LP + l];
        int tau = t - 1;
        v += WF[(size_t)tau * WSZ + DS * LP + l];       // A^tau @ theta0
        int tw = (tau + 62) % 63;
        v += WF[(size_t)tw * WSZ + (49 + b) * LP + l];  // A^{(tau-1)%63} @ sig1_b
      }
    }
    th[l] = v;
  }
  __syncthreads();
  int o = threadIdx.x;
  if (o < OUTD) {
    float tv = ts[bt];
    float acc = th[784 + o];
#pragma unroll
    for (int i = 0; i < 8; ++i) {
      float h = fmaxf(th[i] * tv + th[8 + i], 0.f);
      acc += th[16 + o * 8 + i] * h;
    }
    float rs;
    if (o < DS) rs = tanhf(acc);
    else        rs = fmaxf(acc, 0.f) + log1pf(expf(-fabsf(acc)));
    out[bt * OUTD + o] = rs;
  }
}

extern "C" void kernel_launch(void* const* d_in, const int* in_sizes, int n_in,
                              void* d_out, int out_size, void* d_ws, size_t ws_size,
                              hipStream_t stream) {
  const float* xs  = (const float*)d_in[0];
  const float* ts  = (const float*)d_in[1];
  const float* th0 = (const float*)d_in[2];
  const float* A   = (const float*)d_in[3];
  const float* B   = (const float*)d_in[4];
  float* out = (float*)d_out;
  float* ws  = (float*)d_ws;

  ushort* EP   = (ushort*)(ws + OFF_E);
  const size_t PL = (size_t)LP * LP;
  ushort* EN1  = EP + 0 * PL;
  ushort* ET1  = EP + 1 * PL;
  ushort* EN2  = EP + 2 * PL;
  ushort* ET2  = EP + 3 * PL;
  ushort* EN4  = EP + 4 * PL;
  ushort* ET4  = EP + 5 * PL;
  ushort* EN8  = EP + 6 * PL;
  ushort* ET8  = EP + 7 * PL;
  ushort* EN16 = EP + 8 * PL;
  ushort* ET16 = EP + 9 * PL;
  ushort* EN32 = EP + 10 * PL;
  float*  WF   = ws + OFF_WF;
  ushort* WB   = (ushort*)(ws + OFF_WB);
  ushort* KDT  = (ushort*)(ws + OFF_KDT);   // overlays E planes 0..3 (dead after L5)
  ushort* U    = (ushort*)(ws + OFF_U);
  float*  part = ws + OFF_PART;

  const float c1 = 0.99f;
  const float c2 = c1 * c1, c4 = c2 * c2, c8 = c4 * c4, c16 = c8 * c8, c32 = c16 * c16;

  k_prep<<<978, 256, 0, stream>>>(A, B, th0, xs, EN1, ET1, WF, WB, U);

  // L1..L5: sq E_S -> E_2S (14 rows) || chain W_{t+S} = c_S*W_t + W_t.E_S (S rows)
  k_ladder<<<dim3(14, 15), 512, 0, stream>>>(EN1, ET1, 2.f * c1, EN2, ET2, 14,
                                             1, WB, EN1, c1, WF, WF + 1 * WSZ, WB + (size_t)1 * WSZ,
                                             0, nullptr, nullptr);
  k_ladder<<<dim3(14, 16), 512, 0, stream>>>(EN2, ET2, 2.f * c2, EN4, ET4, 14,
                                             2, WB, EN2, c2, WF, WF + 2 * WSZ, WB + (size_t)2 * WSZ,
                                             0, nullptr, nullptr);
  k_ladder<<<dim3(14, 18), 512, 0, stream>>>(EN4, ET4, 2.f * c4, EN8, ET8, 14,
                                             4, WB, EN4, c4, WF, WF + 4 * WSZ, WB + (size_t)4 * WSZ,
                                             0, nullptr, nullptr);
  k_ladder<<<dim3(14, 22), 512, 0, stream>>>(EN8, ET8, 2.f * c8, EN16, ET16, 14,
                                             8, WB, EN8, c8, WF, WF + 8 * WSZ, WB + (size_t)8 * WSZ,
                                             0, nullptr, nullptr);
  k_ladder<<<dim3(14, 30), 512, 0, stream>>>(EN16, ET16, 2.f * c16, EN32, nullptr, 14,
                                             16, WB, EN16, c16, WF, WF + 16 * WSZ, WB + (size_t)16 * WSZ,
                                             0, nullptr, nullptr);
  // L6: chain W32..62 (31 rows) || kd j=0..31 (32 rows)
  k_ladder<<<dim3(14, 63), 512, 0, stream>>>(nullptr, nullptr, 0.f, nullptr, nullptr, 0,
                                             31, WB, EN32, c32, WF, WF + 32 * WSZ, WB + (size_t)32 * WSZ,
                                             0, WF, KDT);
  // kd j=32..63 (63 -> zero pad)
  k_kd<<<dim3(14, 32), 512, 0, stream>>>(WF, KDT, 32);

  k_conv<<<dim3(14, 4, NZ), 512, 0, stream>>>(U, KDT, part);
  k_final<<<256, 256, 0, stream>>>(part, WF, th0, ts, out);
}